// Round 2
// baseline (168.054 us; speedup 1.0000x reference)
//
#include <hip/hip_runtime.h>
#include <math.h>

// DGCNN forward, algebraically collapsed:
//   out = relu(X_flat @ Meff + const) @ fc2_W + fc2_b
// Meff (310x64) folds BN-scale, S^2 propagation, lin_W, fc1_W;
// const (64) folds BN-shift, lin_b, fc1_b.
//
// Pipeline: k_stats (BN partials) -> k_tp (X transpose + S/S^2, fused grid)
//        -> k_setup (Meff/const)  -> k_gemm (reg-double-buffered, no LDS)
//
// ws layout (floats):
//   [0, 4960)          per-block BN stat partials (496 x 10)
//   [4960, 8928)       S2 (62 x 64, pitch 64)
//   [8928, 28768)      Meff (310 x 64)
//   [28768, 28832)     const (64)
//   [32768, 10190848)  XT (310 x 32768)  ~40.6 MB

#define STATS_BLOCKS 496
#define BN_COUNT 2031616.0f   // B*N = 32768*62

// ---------------------------------------------------------------- K1: BN stats
__global__ __launch_bounds__(256) void k_stats(const float* __restrict__ X,
                                               float* __restrict__ part)
{
    int tid = blockIdx.x * 256 + threadIdx.x;
    const float4* Xv = reinterpret_cast<const float4*>(X) + (size_t)tid * 20;
    float s[5] = {0.f,0.f,0.f,0.f,0.f};
    float q[5] = {0.f,0.f,0.f,0.f,0.f};
#pragma unroll
    for (int v = 0; v < 20; ++v) {
        float4 x = Xv[v];
        s[(4*v+0)%5] += x.x; q[(4*v+0)%5] += x.x*x.x;
        s[(4*v+1)%5] += x.y; q[(4*v+1)%5] += x.y*x.y;
        s[(4*v+2)%5] += x.z; q[(4*v+2)%5] += x.z*x.z;
        s[(4*v+3)%5] += x.w; q[(4*v+3)%5] += x.w*x.w;
    }
#pragma unroll
    for (int k = 0; k < 5; ++k) {
#pragma unroll
        for (int m = 32; m >= 1; m >>= 1) {
            s[k] += __shfl_xor(s[k], m);
            q[k] += __shfl_xor(q[k], m);
        }
    }
    __shared__ float red[4][10];
    int lane = threadIdx.x & 63, w = threadIdx.x >> 6;
    if (lane == 0) {
#pragma unroll
        for (int k = 0; k < 5; ++k) { red[w][k] = s[k]; red[w][5+k] = q[k]; }
    }
    __syncthreads();
    if (threadIdx.x < 10)
        part[blockIdx.x*10 + threadIdx.x] =
            red[0][threadIdx.x] + red[1][threadIdx.x] +
            red[2][threadIdx.x] + red[3][threadIdx.x];
}

// -------------------------- K2: fused {X transpose (blocks 0..511), S^2 (block 512)}
__global__ __launch_bounds__(256) void k_tp(const float* __restrict__ X,
                                            const float* __restrict__ edge,
                                            float* __restrict__ XT,
                                            float* __restrict__ S2g)
{
    __shared__ __align__(16) float lds[4160];
    const int t = threadIdx.x;
    if (blockIdx.x < 512) {
        // transpose 64 rows x 310 cols -> XT[u][row], in 5 chunks of 62 u's
        const int row0 = blockIdx.x * 64;
        for (int cc = 0; cc < 5; ++cc) {
            const int c0 = cc * 62;
            if (cc) __syncthreads();
            for (int i = t; i < 3968; i += 256) {          // coalesced read along u
                int r = i / 62, u = i - r * 62;
                lds[u * 65 + r] = X[(size_t)(row0 + r) * 310 + c0 + u];
            }
            __syncthreads();
            for (int j = t; j < 3968; j += 256) {          // coalesced write along row
                int u = j >> 6, r = j & 63;
                XT[(size_t)(c0 + u) * 32768 + row0 + r] = lds[u * 65 + r];
            }
        }
    } else {
        // single block: build S (62x62, pitch 64, zero-padded) then S2 = S@S
        float* Sm  = lds;          // 62*64
        float* dv  = lds + 3968;   // 64
        float* dis = lds + 4032;   // 64
        for (int e = t; e < 3968; e += 256) {
            int i = e >> 6, j = e & 63;
            float v = 0.f;
            if (j < 62) {
                int idx = (i >= j) ? (i*(i+1)/2 + j) : (j*(j+1)/2 + i);
                v = fmaxf(edge[idx], 0.f);
            }
            Sm[e] = v;
        }
        __syncthreads();
        if (t < 62) {
            float s = 0.f;
            for (int j = 0; j < 64; ++j) s += Sm[t*64 + j];
            dv[t] = 1.0f / sqrtf(s + 1e-10f);
        }
        __syncthreads();
        for (int e = t; e < 3968; e += 256) {
            int i = e >> 6, j = e & 63;
            if (j < 62) Sm[e] *= dv[i] * dv[j];
        }
        __syncthreads();
        if (t < 62) {
            float dg = 1.0f;
            for (int j = 0; j < 64; ++j) dg += fabsf(Sm[t*64 + j]);
            dis[t] = 1.0f / sqrtf(dg);
        }
        __syncthreads();
        for (int e = t; e < 3968; e += 256) {
            int i = e >> 6, j = e & 63;
            if (j < 62) {
                float v = Sm[e] + ((i == j) ? 1.0f : 0.0f);
                Sm[e] = dis[i] * v * dis[j];
            }
        }
        __syncthreads();
        for (int g = t; g < 992; g += 256) {   // 62 rows x 16 float4-col-groups
            int i = g >> 4, j0 = (g & 15) << 2;
            float4 acc = {0.f, 0.f, 0.f, 0.f};
            for (int k = 0; k < 62; ++k) {
                float s = Sm[i*64 + k];
                float4 b = *reinterpret_cast<const float4*>(&Sm[k*64 + j0]);
                acc.x += s*b.x; acc.y += s*b.y; acc.z += s*b.z; acc.w += s*b.w;
            }
            *reinterpret_cast<float4*>(&S2g[i*64 + j0]) = acc;
        }
    }
}

// ------------------------------------------------- K3: build Meff + const
// one block per output column o of fc1 (64 blocks x 256 threads)
__global__ __launch_bounds__(256) void k_setup(
    const float* __restrict__ part, const float* __restrict__ S2g,
    const float* __restrict__ gamma, const float* __restrict__ beta,
    const float* __restrict__ linW, const float* __restrict__ linb,
    const float* __restrict__ fc1W, const float* __restrict__ fc1b,
    float* __restrict__ Meff, float* __restrict__ constv)
{
    const int o = blockIdx.x;
    const int t = threadIdx.x;
    __shared__ float S2m[3968];     // S2, pitch 64
    __shared__ float colo[3968];    // fc1_W[:, o]
    __shared__ float Tm[310];       // T[n*5+f] = sum_h lin_W[f,h] fc1W[n*64+h, o]
    __shared__ float lw[320];
    __shared__ float scale[5], shift[5];
    __shared__ float redbuf[256];

    {   // BN stats reduce
        float st[10];
#pragma unroll
        for (int k = 0; k < 10; ++k) st[k] = 0.f;
        for (int b = t; b < STATS_BLOCKS; b += 256) {
#pragma unroll
            for (int k = 0; k < 10; ++k) st[k] += part[b*10 + k];
        }
#pragma unroll
        for (int k = 0; k < 10; ++k) {
#pragma unroll
            for (int m = 32; m >= 1; m >>= 1) st[k] += __shfl_xor(st[k], m);
        }
        int lane = t & 63, w = t >> 6;
        if (lane == 0)
            for (int k = 0; k < 10; ++k) redbuf[w*10 + k] = st[k];
    }
    for (int i = t; i < 3968; i += 256) {
        S2m[i]  = S2g[i];
        colo[i] = fc1W[(size_t)i*64 + o];
    }
    for (int i = t; i < 320; i += 256) lw[i] = linW[i];
    __syncthreads();

    if (t < 10)
        redbuf[64 + t] = redbuf[t] + redbuf[10+t] + redbuf[20+t] + redbuf[30+t];
    __syncthreads();
    if (t < 5) {
        float mean = redbuf[64 + t] * (1.0f / BN_COUNT);
        float var  = redbuf[69 + t] * (1.0f / BN_COUNT) - mean*mean;
        float inv  = 1.0f / sqrtf(var + 1e-5f);
        scale[t] = gamma[t] * inv;
        shift[t] = beta[t] - mean * gamma[t] * inv;
    }
    // T[n,f] = sum_h lin_W[f,h] * fc1W[n*64+h, o]
    for (int p = t; p < 310; p += 256) {
        int n = p / 5, f = p - n*5;
        float sum = 0.f;
        for (int h = 0; h < 64; ++h) sum += lw[f*64 + h] * colo[n*64 + h];
        Tm[p] = sum;
    }
    __syncthreads();
    // M[j,f] = sum_n S2[n,j] T[n,f]; Meff = scale[f]*M; const partials
    float cpart = 0.f;
    for (int p = t; p < 310; p += 256) {
        int j = p / 5, f = p - j*5;
        float m = 0.f;
        for (int n = 0; n < 62; ++n) m += S2m[n*64 + j] * Tm[n*5 + f];
        Meff[(size_t)p*64 + o] = scale[f] * m;
        cpart += shift[f] * m;
    }
    for (int nh = t; nh < 3968; nh += 256)
        cpart += linb[nh & 63] * colo[nh];
    __syncthreads();
    redbuf[t] = cpart;
    __syncthreads();
    for (int sft = 128; sft > 0; sft >>= 1) {
        if (t < sft) redbuf[t] += redbuf[t + sft];
        __syncthreads();
    }
    if (t == 0) constv[o] = redbuf[0] + fc1b[o];
}

// ------------------- K4: GEMM (no LDS) + relu + fc2, register double-buffered
// 512 blocks x 256 thr; block = 64 rows x 64 cols; thread = 4 rows x 4 cols.
// x from XT (coalesced+broadcast), m from Meff (L2-resident); chunks of 5 u's.
struct Ch { float4 xa[5]; float4 m[5]; };

__device__ __forceinline__ void ldch(Ch& c, const float* px, const float* pm, int u0) {
#pragma unroll
    for (int k = 0; k < 5; ++k) {
        c.xa[k] = *reinterpret_cast<const float4*>(px + (size_t)(u0 + k) * 32768);
        c.m[k]  = *reinterpret_cast<const float4*>(pm + (u0 + k) * 64);
    }
}

__device__ __forceinline__ void fmach(float acc[4][4], const Ch& c) {
#pragma unroll
    for (int k = 0; k < 5; ++k) {
        float4 x = c.xa[k], m = c.m[k];
        acc[0][0] += x.x*m.x; acc[0][1] += x.x*m.y; acc[0][2] += x.x*m.z; acc[0][3] += x.x*m.w;
        acc[1][0] += x.y*m.x; acc[1][1] += x.y*m.y; acc[1][2] += x.y*m.z; acc[1][3] += x.y*m.w;
        acc[2][0] += x.z*m.x; acc[2][1] += x.z*m.y; acc[2][2] += x.z*m.z; acc[2][3] += x.z*m.w;
        acc[3][0] += x.w*m.x; acc[3][1] += x.w*m.y; acc[3][2] += x.w*m.z; acc[3][3] += x.w*m.w;
    }
}

__global__ __launch_bounds__(256, 2) void k_gemm(
    const float* __restrict__ XT, const float* __restrict__ Meff,
    const float* __restrict__ constv, const float* __restrict__ fc2W,
    const float* __restrict__ fc2b, float* __restrict__ out)
{
    const int t = threadIdx.x;
    const int tc = t & 15;          // cols tc*4..+3
    const int tr = t >> 4;          // rows tr*4..+3
    const int row0 = blockIdx.x * 64;
    const float* px = XT + row0 + tr * 4;
    const float* pm = Meff + tc * 4;
    float acc[4][4];
#pragma unroll
    for (int a = 0; a < 4; ++a)
#pragma unroll
        for (int b = 0; b < 4; ++b) acc[a][b] = 0.f;

    Ch A, B;
    ldch(A, px, pm, 0);
#pragma unroll 1
    for (int i = 0; i < 30; ++i) {
        ldch(B, px, pm, 5);
        fmach(acc, A);
        px += 10 * 32768; pm += 10 * 64;
        ldch(A, px, pm, 0);
        fmach(acc, B);
    }
    ldch(B, px, pm, 5);
    fmach(acc, A);
    fmach(acc, B);

    // epilogue: +const, relu, x fc2 (64x3), reduce over the 16 col-threads
    float cst[4], f2r[4][3];
#pragma unroll
    for (int j = 0; j < 4; ++j) {
        int col = tc*4 + j;
        cst[j]    = constv[col];
        f2r[j][0] = fc2W[col*3 + 0];
        f2r[j][1] = fc2W[col*3 + 1];
        f2r[j][2] = fc2W[col*3 + 2];
    }
    float prt[4][3];
#pragma unroll
    for (int q = 0; q < 4; ++q) { prt[q][0] = prt[q][1] = prt[q][2] = 0.f; }
#pragma unroll
    for (int q = 0; q < 4; ++q) {
#pragma unroll
        for (int j = 0; j < 4; ++j) {
            float z = fmaxf(acc[q][j] + cst[j], 0.f);
            prt[q][0] += z * f2r[j][0];
            prt[q][1] += z * f2r[j][1];
            prt[q][2] += z * f2r[j][2];
        }
    }
#pragma unroll
    for (int m = 1; m < 16; m <<= 1) {
#pragma unroll
        for (int q = 0; q < 4; ++q) {
            prt[q][0] += __shfl_xor(prt[q][0], m);
            prt[q][1] += __shfl_xor(prt[q][1], m);
            prt[q][2] += __shfl_xor(prt[q][2], m);
        }
    }
    if (tc == 0) {
        float b0 = fc2b[0], b1 = fc2b[1], b2 = fc2b[2];
#pragma unroll
        for (int q = 0; q < 4; ++q) {
            size_t rw = (size_t)(row0 + tr*4 + q) * 3;
            out[rw + 0] = prt[q][0] + b0;
            out[rw + 1] = prt[q][1] + b1;
            out[rw + 2] = prt[q][2] + b2;
        }
    }
}

extern "C" void kernel_launch(void* const* d_in, const int* in_sizes, int n_in,
                              void* d_out, int out_size, void* d_ws, size_t ws_size,
                              hipStream_t stream)
{
    const float* X     = (const float*)d_in[0];
    const float* edge  = (const float*)d_in[1];
    const float* gamma = (const float*)d_in[2];
    const float* beta  = (const float*)d_in[3];
    const float* linW  = (const float*)d_in[4];
    const float* linb  = (const float*)d_in[5];
    const float* fc1W  = (const float*)d_in[6];
    const float* fc1b  = (const float*)d_in[7];
    const float* fc2W  = (const float*)d_in[8];
    const float* fc2b  = (const float*)d_in[9];
    float* out = (float*)d_out;
    float* ws  = (float*)d_ws;

    float* part   = ws;            // 496*10
    float* S2g    = ws + 4960;     // 62*64
    float* Meff   = ws + 8928;     // 310*64
    float* constv = ws + 28768;    // 64
    float* XT     = ws + 32768;    // 310*32768

    hipLaunchKernelGGL(k_stats, dim3(496), dim3(256), 0, stream, X, part);
    hipLaunchKernelGGL(k_tp,    dim3(513), dim3(256), 0, stream, X, edge, XT, S2g);
    hipLaunchKernelGGL(k_setup, dim3(64),  dim3(256), 0, stream,
                       part, S2g, gamma, beta, linW, linb, fc1W, fc1b, Meff, constv);
    hipLaunchKernelGGL(k_gemm,  dim3(512), dim3(256), 0, stream,
                       XT, Meff, constv, fc2W, fc2b, out);
}

// Round 3
// 143.097 us; speedup vs baseline: 1.1744x; 1.1744x over previous
//
#include <hip/hip_runtime.h>
#include <math.h>

// DGCNN forward, algebraically collapsed:
//   out = relu(X_flat @ Meff + const) @ fc2_W + fc2_b
// Meff (310x64) folds BN-scale, S^2, lin_W, fc1_W; const folds shifts/biases.
// GEMM runs on MFMA via split-bf16: x=hi+lo, M=hi+lo, acc = hi*hi+hi*lo+lo*hi.
//
// Pipeline:
//   k_conv : X -> BN stat partials + packed bf16 A-fragments (hi/lo planes);
//            extra block builds S^2
//   k_setup: stats -> scale/shift; T; MeffT (64x320, zero-padded); const
//   k_pack : MeffT -> packed bf16 B-fragments (hi/lo)
//   k_gemm : 16x16x32 bf16 MFMA, wave = 32 rows x 64 cols, K=320,
//            fused relu + fc2 epilogue
//
// ws layout (floats):
//   [0,10240)            BN stat partials (1024 x 10)
//   [10240,14208)        S2 (62x64, pitch 64)
//   [14208,34688)        MeffT (64 x 320)
//   [34688,34752)        const (64)
//   [34816,45056)        Bhi frags (4nt x 10ks x 64lane x 16B)
//   [45056,55296)        Blo frags
//   [65536,5308416)      Ahi frags (2048mt x 10ks x 64lane x 16B) ~21MB
//   [5308416,10551296)   Alo frags ~21MB

typedef __bf16 bf16_t;
typedef __attribute__((ext_vector_type(8))) __bf16 bf16x8;
typedef __attribute__((ext_vector_type(4))) float f32x4;

#define BN_COUNT 2031616.0f   // B*N = 32768*62

// --------------------- K1: X -> stats partials + packed A frags; S^2 block
__global__ __launch_bounds__(256) void k_conv(const float* __restrict__ X,
                                              const float* __restrict__ edge,
                                              float* __restrict__ part,
                                              bf16x8* __restrict__ Ahi,
                                              bf16x8* __restrict__ Alo,
                                              float* __restrict__ S2g)
{
    __shared__ float lds[32 * 312];   // 39936 B
    const int t = threadIdx.x;
    if (blockIdx.x < 1024) {
        const float* Xb = X + (size_t)blockIdx.x * 32 * 310;
        float s0=0,s1=0,s2=0,s3=0,s4=0,q0=0,q1=0,q2=0,q3=0,q4=0;
        for (int i = t; i < 4960; i += 256) {         // 32 rows x 155 float2
            int row = i / 155;
            int cc  = i - row * 155;
            float2 v = *reinterpret_cast<const float2*>(Xb + (size_t)row*310 + 2*cc);
            lds[row*312 + 2*cc]     = v.x;
            lds[row*312 + 2*cc + 1] = v.y;
            int f0 = (2*cc) % 5;
            int f1 = (f0 == 4) ? 0 : f0 + 1;
            float xx = v.x*v.x, yy = v.y*v.y;
            s0 += (f0==0)?v.x:0.f; s1 += (f0==1)?v.x:0.f; s2 += (f0==2)?v.x:0.f;
            s3 += (f0==3)?v.x:0.f; s4 += (f0==4)?v.x:0.f;
            q0 += (f0==0)?xx:0.f;  q1 += (f0==1)?xx:0.f;  q2 += (f0==2)?xx:0.f;
            q3 += (f0==3)?xx:0.f;  q4 += (f0==4)?xx:0.f;
            s0 += (f1==0)?v.y:0.f; s1 += (f1==1)?v.y:0.f; s2 += (f1==2)?v.y:0.f;
            s3 += (f1==3)?v.y:0.f; s4 += (f1==4)?v.y:0.f;
            q0 += (f1==0)?yy:0.f;  q1 += (f1==1)?yy:0.f;  q2 += (f1==2)?yy:0.f;
            q3 += (f1==3)?yy:0.f;  q4 += (f1==4)?yy:0.f;
        }
        // wave reduce 10 values
        float st[10] = {s0,s1,s2,s3,s4,q0,q1,q2,q3,q4};
#pragma unroll
        for (int k = 0; k < 10; ++k)
#pragma unroll
            for (int m = 32; m >= 1; m >>= 1) st[k] += __shfl_xor(st[k], m);
        __shared__ float red[4][10];
        int lane = t & 63, w = t >> 6;
        if (lane == 0)
#pragma unroll
            for (int k = 0; k < 10; ++k) red[w][k] = st[k];
        __syncthreads();
        if (t < 10)
            part[blockIdx.x*10 + t] = red[0][t] + red[1][t] + red[2][t] + red[3][t];
        // phase 2: pack A fragments (2 mtiles x 10 ksteps x 64 lanes)
        const int mt0 = blockIdx.x * 2;
        for (int i = t; i < 1280; i += 256) {
            int mt   = i / 640;
            int rem  = i - mt * 640;
            int ks   = rem >> 6;
            int lane2 = rem & 63;
            int row  = (mt << 4) + (lane2 & 15);
            int k0   = ks * 32 + ((lane2 >> 4) << 3);
            bf16x8 h8, l8;
#pragma unroll
            for (int j = 0; j < 8; ++j) {
                int k = k0 + j;
                float val = (k < 310) ? lds[row*312 + k] : 0.f;
                __bf16 h = (__bf16)val;
                h8[j] = h;
                l8[j] = (__bf16)(val - (float)h);
            }
            size_t idx = (size_t)(mt0 + mt) * 640 + ks * 64 + lane2;
            Ahi[idx] = h8;
            Alo[idx] = l8;
        }
    } else {
        // single block: build S (62x62, pitch 64, zero-padded) then S2 = S@S
        float* Sm  = lds;          // 62*64
        float* dv  = lds + 3968;   // 64
        float* dis = lds + 4032;   // 64
        for (int e = t; e < 3968; e += 256) {
            int i = e >> 6, j = e & 63;
            float v = 0.f;
            if (j < 62) {
                int idx = (i >= j) ? (i*(i+1)/2 + j) : (j*(j+1)/2 + i);
                v = fmaxf(edge[idx], 0.f);
            }
            Sm[e] = v;
        }
        __syncthreads();
        if (t < 62) {
            float s = 0.f;
            for (int j = 0; j < 64; ++j) s += Sm[t*64 + j];
            dv[t] = 1.0f / sqrtf(s + 1e-10f);
        }
        __syncthreads();
        for (int e = t; e < 3968; e += 256) {
            int i = e >> 6, j = e & 63;
            if (j < 62) Sm[e] *= dv[i] * dv[j];
        }
        __syncthreads();
        if (t < 62) {
            float dg = 1.0f;
            for (int j = 0; j < 64; ++j) dg += fabsf(Sm[t*64 + j]);
            dis[t] = 1.0f / sqrtf(dg);
        }
        __syncthreads();
        for (int e = t; e < 3968; e += 256) {
            int i = e >> 6, j = e & 63;
            if (j < 62) {
                float v = Sm[e] + ((i == j) ? 1.0f : 0.0f);
                Sm[e] = dis[i] * v * dis[j];
            }
        }
        __syncthreads();
        for (int g = t; g < 992; g += 256) {
            int i = g >> 4, j0 = (g & 15) << 2;
            float4 acc = {0.f, 0.f, 0.f, 0.f};
            for (int k = 0; k < 62; ++k) {
                float s = Sm[i*64 + k];
                float4 b = *reinterpret_cast<const float4*>(&Sm[k*64 + j0]);
                acc.x += s*b.x; acc.y += s*b.y; acc.z += s*b.z; acc.w += s*b.w;
            }
            *reinterpret_cast<float4*>(&S2g[i*64 + j0]) = acc;
        }
    }
}

// ------------------------------------------------- K2: build MeffT + const
__global__ __launch_bounds__(256) void k_setup(
    const float* __restrict__ part, const float* __restrict__ S2g,
    const float* __restrict__ gamma, const float* __restrict__ beta,
    const float* __restrict__ linW, const float* __restrict__ linb,
    const float* __restrict__ fc1W, const float* __restrict__ fc1b,
    float* __restrict__ MeffT, float* __restrict__ constv)
{
    const int o = blockIdx.x;
    const int t = threadIdx.x;
    __shared__ float S2m[3968];
    __shared__ float colo[3968];
    __shared__ float Tm[310];
    __shared__ float lw[320];
    __shared__ float scale[5], shift[5];
    __shared__ float redbuf[256];

    {   // BN stats reduce over 1024 partials
        float st[10];
#pragma unroll
        for (int k = 0; k < 10; ++k) st[k] = 0.f;
        for (int b = t; b < 1024; b += 256)
#pragma unroll
            for (int k = 0; k < 10; ++k) st[k] += part[b*10 + k];
#pragma unroll
        for (int k = 0; k < 10; ++k)
#pragma unroll
            for (int m = 32; m >= 1; m >>= 1) st[k] += __shfl_xor(st[k], m);
        int lane = t & 63, w = t >> 6;
        if (lane == 0)
            for (int k = 0; k < 10; ++k) redbuf[w*10 + k] = st[k];
    }
    for (int i = t; i < 3968; i += 256) {
        S2m[i]  = S2g[i];
        colo[i] = fc1W[(size_t)i*64 + o];
    }
    for (int i = t; i < 320; i += 256) lw[i] = linW[i];
    __syncthreads();

    if (t < 10)
        redbuf[64 + t] = redbuf[t] + redbuf[10+t] + redbuf[20+t] + redbuf[30+t];
    __syncthreads();
    if (t < 5) {
        float mean = redbuf[64 + t] * (1.0f / BN_COUNT);
        float var  = redbuf[69 + t] * (1.0f / BN_COUNT) - mean*mean;
        float inv  = 1.0f / sqrtf(var + 1e-5f);
        scale[t] = gamma[t] * inv;
        shift[t] = beta[t] - mean * gamma[t] * inv;
    }
    for (int p = t; p < 310; p += 256) {
        int n = p / 5, f = p - n*5;
        float sum = 0.f;
        for (int h = 0; h < 64; ++h) sum += lw[f*64 + h] * colo[n*64 + h];
        Tm[p] = sum;
    }
    __syncthreads();
    float cpart = 0.f;
    for (int p = t; p < 310; p += 256) {
        int j = p / 5, f = p - j*5;
        float m = 0.f;
        for (int n = 0; n < 62; ++n) m += S2m[n*64 + j] * Tm[n*5 + f];
        MeffT[o*320 + p] = scale[f] * m;
        cpart += shift[f] * m;
    }
    if (t < 10) MeffT[o*320 + 310 + t] = 0.f;   // zero-pad K to 320
    for (int nh = t; nh < 3968; nh += 256)
        cpart += linb[nh & 63] * colo[nh];
    __syncthreads();
    redbuf[t] = cpart;
    __syncthreads();
    for (int sft = 128; sft > 0; sft >>= 1) {
        if (t < sft) redbuf[t] += redbuf[t + sft];
        __syncthreads();
    }
    if (t == 0) constv[o] = redbuf[0] + fc1b[o];
}

// ------------------------------------- K3: pack B fragments (hi/lo) from MeffT
__global__ __launch_bounds__(64) void k_pack(const float* __restrict__ MeffT,
                                             bf16x8* __restrict__ Bhi,
                                             bf16x8* __restrict__ Blo)
{
    const int b  = blockIdx.x;      // 0..39
    const int nt = b / 10;
    const int ks = b - nt * 10;
    const int lane = threadIdx.x;
    const int col = nt*16 + (lane & 15);
    const int k0  = ks*32 + ((lane >> 4) << 3);
    bf16x8 h8, l8;
#pragma unroll
    for (int j = 0; j < 8; ++j) {
        float val = MeffT[col*320 + k0 + j];
        __bf16 h = (__bf16)val;
        h8[j] = h;
        l8[j] = (__bf16)(val - (float)h);
    }
    Bhi[(nt*10 + ks)*64 + lane] = h8;
    Blo[(nt*10 + ks)*64 + lane] = l8;
}

// --------------- K4: MFMA GEMM (split-bf16) + relu + fc2 epilogue
// 256 blocks x 256 thr (4 waves); wave = 32 rows x 64 cols, K=320.
__global__ __launch_bounds__(256) void k_gemm(
    const bf16x8* __restrict__ Ahi, const bf16x8* __restrict__ Alo,
    const bf16x8* __restrict__ Bhi, const bf16x8* __restrict__ Blo,
    const float* __restrict__ constv, const float* __restrict__ fc2W,
    const float* __restrict__ fc2b, float* __restrict__ out)
{
    const int t = threadIdx.x;
    const int lane = t & 63;
    const int waveId = blockIdx.x * 4 + (t >> 6);   // 0..1023
    const bf16x8* pAh = Ahi + (size_t)waveId * 1280 + lane;
    const bf16x8* pAl = Alo + (size_t)waveId * 1280 + lane;
    const bf16x8* pBh = Bhi + lane;
    const bf16x8* pBl = Blo + lane;

    f32x4 acc[2][4];
#pragma unroll
    for (int m = 0; m < 2; ++m)
#pragma unroll
        for (int n = 0; n < 4; ++n) acc[m][n] = (f32x4){0.f,0.f,0.f,0.f};

    bf16x8 ah[2][2], al[2][2], bh[2][4], bl[2][4];
#define LOAD_KS(B_, KS_) do {                                            \
        ah[B_][0] = pAh[(KS_)*64];        ah[B_][1] = pAh[640 + (KS_)*64]; \
        al[B_][0] = pAl[(KS_)*64];        al[B_][1] = pAl[640 + (KS_)*64]; \
        bh[B_][0] = pBh[(KS_)*64];        bh[B_][1] = pBh[(10+(KS_))*64];  \
        bh[B_][2] = pBh[(20+(KS_))*64];   bh[B_][3] = pBh[(30+(KS_))*64];  \
        bl[B_][0] = pBl[(KS_)*64];        bl[B_][1] = pBl[(10+(KS_))*64];  \
        bl[B_][2] = pBl[(20+(KS_))*64];   bl[B_][3] = pBl[(30+(KS_))*64];  \
    } while (0)

    LOAD_KS(0, 0);
#pragma unroll
    for (int ks = 0; ks < 10; ++ks) {
        if (ks < 9) {
            if ((ks & 1) == 0) LOAD_KS(1, ks + 1);
            else               LOAD_KS(0, ks + 1);
        }
        const int bb = ks & 1;   // constant after full unroll
#pragma unroll
        for (int m = 0; m < 2; ++m)
#pragma unroll
            for (int n = 0; n < 4; ++n) {
                acc[m][n] = __builtin_amdgcn_mfma_f32_16x16x32_bf16(ah[bb][m], bh[bb][n], acc[m][n], 0, 0, 0);
                acc[m][n] = __builtin_amdgcn_mfma_f32_16x16x32_bf16(ah[bb][m], bl[bb][n], acc[m][n], 0, 0, 0);
                acc[m][n] = __builtin_amdgcn_mfma_f32_16x16x32_bf16(al[bb][m], bh[bb][n], acc[m][n], 0, 0, 0);
            }
    }
#undef LOAD_KS

    // epilogue: z = relu(acc + const[col]); out3 = z @ fc2 (reduce 16 col-lanes)
    const int cl = lane & 15;
    float cst[4], f2r[4][3];
#pragma unroll
    for (int n = 0; n < 4; ++n) {
        int col = n*16 + cl;
        cst[n]    = constv[col];
        f2r[n][0] = fc2W[col*3 + 0];
        f2r[n][1] = fc2W[col*3 + 1];
        f2r[n][2] = fc2W[col*3 + 2];
    }
    float b0 = fc2b[0], b1 = fc2b[1], b2 = fc2b[2];
#pragma unroll
    for (int m = 0; m < 2; ++m) {
#pragma unroll
        for (int r = 0; r < 4; ++r) {
            float p0 = 0.f, p1 = 0.f, p2 = 0.f;
#pragma unroll
            for (int n = 0; n < 4; ++n) {
                float z = fmaxf(acc[m][n][r] + cst[n], 0.f);
                p0 += z * f2r[n][0];
                p1 += z * f2r[n][1];
                p2 += z * f2r[n][2];
            }
#pragma unroll
            for (int msk = 1; msk < 16; msk <<= 1) {
                p0 += __shfl_xor(p0, msk);
                p1 += __shfl_xor(p1, msk);
                p2 += __shfl_xor(p2, msk);
            }
            if (cl == 0) {
                int row = waveId*32 + m*16 + (lane >> 4)*4 + r;
                size_t rw = (size_t)row * 3;
                out[rw + 0] = p0 + b0;
                out[rw + 1] = p1 + b1;
                out[rw + 2] = p2 + b2;
            }
        }
    }
}

extern "C" void kernel_launch(void* const* d_in, const int* in_sizes, int n_in,
                              void* d_out, int out_size, void* d_ws, size_t ws_size,
                              hipStream_t stream)
{
    const float* X     = (const float*)d_in[0];
    const float* edge  = (const float*)d_in[1];
    const float* gamma = (const float*)d_in[2];
    const float* beta  = (const float*)d_in[3];
    const float* linW  = (const float*)d_in[4];
    const float* linb  = (const float*)d_in[5];
    const float* fc1W  = (const float*)d_in[6];
    const float* fc1b  = (const float*)d_in[7];
    const float* fc2W  = (const float*)d_in[8];
    const float* fc2b  = (const float*)d_in[9];
    float* out = (float*)d_out;
    float* ws  = (float*)d_ws;

    float*  part   = ws;                       // 1024*10
    float*  S2g    = ws + 10240;               // 62*64
    float*  MeffT  = ws + 14208;               // 64*320
    float*  constv = ws + 34688;               // 64
    bf16x8* Bhi    = (bf16x8*)(ws + 34816);    // 2560 chunks
    bf16x8* Blo    = (bf16x8*)(ws + 45056);
    bf16x8* Ahi    = (bf16x8*)(ws + 65536);    // 2048*10*64 chunks
    bf16x8* Alo    = (bf16x8*)(ws + 5308416);

    hipLaunchKernelGGL(k_conv,  dim3(1025), dim3(256), 0, stream,
                       X, edge, part, Ahi, Alo, S2g);
    hipLaunchKernelGGL(k_setup, dim3(64),   dim3(256), 0, stream,
                       part, S2g, gamma, beta, linW, linb, fc1W, fc1b, MeffT, constv);
    hipLaunchKernelGGL(k_pack,  dim3(40),   dim3(64),  0, stream, MeffT, Bhi, Blo);
    hipLaunchKernelGGL(k_gemm,  dim3(256),  dim3(256), 0, stream,
                       Ahi, Alo, Bhi, Blo, constv, fc2W, fc2b, out);
}

// Round 5
// 129.192 us; speedup vs baseline: 1.3008x; 1.1076x over previous
//
#include <hip/hip_runtime.h>
#include <math.h>

// DGCNN forward, algebraically collapsed:
//   out = relu(X_flat @ Meff + const) @ fc2_W + fc2_b
// Meff (310x64) folds BN-scale, S^2, lin_W, fc1_W; const folds shifts/biases.
// GEMM on MFMA via split-bf16: x=hi+lo, M=hi+lo, acc = hi*hi + hi*lo + lo*hi.
//
// Pipeline (3 kernels):
//   k_stats : X -> BN stat partials (blocks 0..495); block 496 builds S^2
//   k_setup : stats -> scale/shift; T; B-fragments (bf16 hi/lo) + const
//   k_gemm  : A-fragments formed IN-REGISTER from X (float2 loads, on-the-fly
//             hi/lo split), 16x16x32 bf16 MFMA, K=320, fused relu+fc2 epilogue
//
// ws layout (floats):
//   [0,4960)        BN stat partials (496 x 10)
//   [4960,8928)     S2 (62x64, pitch 64)
//   [8928,8992)     const (64)
//   [8992,19232)    Bhi frags (4nt x 10ks x 64lane x 16B)
//   [19232,29472)   Blo frags

typedef __attribute__((ext_vector_type(8))) __bf16 bf16x8;
typedef __attribute__((ext_vector_type(4))) float f32x4;

#define BN_COUNT 2031616.0f   // B*N = 32768*62

// --------------------- K1: BN stat partials; block 496 builds S^2
__global__ __launch_bounds__(256) void k_stats(const float* __restrict__ X,
                                               const float* __restrict__ edge,
                                               float* __restrict__ part,
                                               float* __restrict__ S2g)
{
    __shared__ __align__(16) float lds[4160];
    const int t = threadIdx.x;
    if (blockIdx.x < 496) {
        int tid = blockIdx.x * 256 + t;
        const float4* Xv = reinterpret_cast<const float4*>(X) + (size_t)tid * 20;
        float s[5] = {0.f,0.f,0.f,0.f,0.f};
        float q[5] = {0.f,0.f,0.f,0.f,0.f};
#pragma unroll
        for (int v = 0; v < 20; ++v) {
            float4 x = Xv[v];
            s[(4*v+0)%5] += x.x; q[(4*v+0)%5] += x.x*x.x;
            s[(4*v+1)%5] += x.y; q[(4*v+1)%5] += x.y*x.y;
            s[(4*v+2)%5] += x.z; q[(4*v+2)%5] += x.z*x.z;
            s[(4*v+3)%5] += x.w; q[(4*v+3)%5] += x.w*x.w;
        }
#pragma unroll
        for (int k = 0; k < 5; ++k)
#pragma unroll
            for (int m = 32; m >= 1; m >>= 1) {
                s[k] += __shfl_xor(s[k], m);
                q[k] += __shfl_xor(q[k], m);
            }
        int lane = t & 63, w = t >> 6;
        if (lane == 0) {
#pragma unroll
            for (int k = 0; k < 5; ++k) { lds[w*10+k] = s[k]; lds[w*10+5+k] = q[k]; }
        }
        __syncthreads();
        if (t < 10)
            part[blockIdx.x*10 + t] = lds[t] + lds[10+t] + lds[20+t] + lds[30+t];
    } else {
        // build S (62x62, pitch 64, zero-padded) then S2 = S@S
        float* Sm  = lds;          // 62*64
        float* dv  = lds + 3968;   // 64
        float* dis = lds + 4032;   // 64
        for (int e = t; e < 3968; e += 256) {
            int i = e >> 6, j = e & 63;
            float v = 0.f;
            if (j < 62) {
                int idx = (i >= j) ? (i*(i+1)/2 + j) : (j*(j+1)/2 + i);
                v = fmaxf(edge[idx], 0.f);
            }
            Sm[e] = v;
        }
        __syncthreads();
        if (t < 62) {
            float s = 0.f;
            for (int j = 0; j < 64; ++j) s += Sm[t*64 + j];
            dv[t] = 1.0f / sqrtf(s + 1e-10f);
        }
        __syncthreads();
        for (int e = t; e < 3968; e += 256) {
            int i = e >> 6, j = e & 63;
            if (j < 62) Sm[e] *= dv[i] * dv[j];
        }
        __syncthreads();
        if (t < 62) {
            float dg = 1.0f;
            for (int j = 0; j < 64; ++j) dg += fabsf(Sm[t*64 + j]);
            dis[t] = 1.0f / sqrtf(dg);
        }
        __syncthreads();
        for (int e = t; e < 3968; e += 256) {
            int i = e >> 6, j = e & 63;
            if (j < 62) {
                float v = Sm[e] + ((i == j) ? 1.0f : 0.0f);
                Sm[e] = dis[i] * v * dis[j];
            }
        }
        __syncthreads();
        for (int g = t; g < 992; g += 256) {
            int i = g >> 4, j0 = (g & 15) << 2;
            float4 acc = {0.f, 0.f, 0.f, 0.f};
            for (int k = 0; k < 62; ++k) {
                float s = Sm[i*64 + k];
                float4 b = *reinterpret_cast<const float4*>(&Sm[k*64 + j0]);
                acc.x += s*b.x; acc.y += s*b.y; acc.z += s*b.z; acc.w += s*b.w;
            }
            *reinterpret_cast<float4*>(&S2g[i*64 + j0]) = acc;
        }
    }
}

// ------------------- K2: build B fragments (bf16 hi/lo) + const; 64 blocks
__global__ __launch_bounds__(256) void k_setup(
    const float* __restrict__ part, const float* __restrict__ S2g,
    const float* __restrict__ gamma, const float* __restrict__ beta,
    const float* __restrict__ linW, const float* __restrict__ linb,
    const float* __restrict__ fc1W, const float* __restrict__ fc1b,
    __bf16* __restrict__ Bhi, __bf16* __restrict__ Blo,
    float* __restrict__ constv)
{
    const int o = blockIdx.x;
    const int t = threadIdx.x;
    __shared__ float S2m[3968];
    __shared__ float colo[3968];
    __shared__ float Tm[310];
    __shared__ float lw[320];
    __shared__ float scale[5], shift[5];
    __shared__ float redbuf[256];

    {   // BN stats reduce over 496 partials
        float st[10];
#pragma unroll
        for (int k = 0; k < 10; ++k) st[k] = 0.f;
        for (int b = t; b < 496; b += 256)
#pragma unroll
            for (int k = 0; k < 10; ++k) st[k] += part[b*10 + k];
#pragma unroll
        for (int k = 0; k < 10; ++k)
#pragma unroll
            for (int m = 32; m >= 1; m >>= 1) st[k] += __shfl_xor(st[k], m);
        int lane = t & 63, w = t >> 6;
        if (lane == 0)
            for (int k = 0; k < 10; ++k) redbuf[w*10 + k] = st[k];
    }
    for (int i = t; i < 3968; i += 256) {
        S2m[i]  = S2g[i];
        colo[i] = fc1W[(size_t)i*64 + o];
    }
    for (int i = t; i < 320; i += 256) lw[i] = linW[i];
    __syncthreads();

    if (t < 10)
        redbuf[64 + t] = redbuf[t] + redbuf[10+t] + redbuf[20+t] + redbuf[30+t];
    __syncthreads();
    if (t < 5) {
        float mean = redbuf[64 + t] * (1.0f / BN_COUNT);
        float var  = redbuf[69 + t] * (1.0f / BN_COUNT) - mean*mean;
        float inv  = 1.0f / sqrtf(var + 1e-5f);
        scale[t] = gamma[t] * inv;
        shift[t] = beta[t] - mean * gamma[t] * inv;
    }
    // T[n,f] = sum_h lin_W[f,h] * fc1W[n*64+h, o]
    for (int p = t; p < 310; p += 256) {
        int n = p / 5, f = p - n*5;
        float sum = 0.f;
        for (int h = 0; h < 64; ++h) sum += lw[f*64 + h] * colo[n*64 + h];
        Tm[p] = sum;
    }
    __syncthreads();
    // Meff[p] = scale[f] * sum_n S2[n,nd] T[n,f]  (p = nd*5+f = k index)
    // written directly as bf16 hi/lo B-fragments
    const int nt = o >> 4;
    const int cl = o & 15;
    float cpart = 0.f;
    for (int p = t; p < 310; p += 256) {
        int nd = p / 5, f = p - nd*5;
        float m = 0.f;
        for (int n = 0; n < 62; ++n) m += S2m[n*64 + nd] * Tm[n*5 + f];
        float val = scale[f] * m;
        cpart += shift[f] * m;
        int ks = p >> 5, qq = (p >> 3) & 3, jj = p & 7;
        int ln = (qq << 4) | cl;
        size_t fo = ((size_t)(nt*10 + ks)*64 + ln)*8 + jj;
        __bf16 h = (__bf16)val;
        Bhi[fo] = h;
        Blo[fo] = (__bf16)(val - (float)h);
    }
    if (t < 10) {                       // zero-pad k = 310..319
        int p = 310 + t;
        int ks = p >> 5, qq = (p >> 3) & 3, jj = p & 7;
        int ln = (qq << 4) | cl;
        size_t fo = ((size_t)(nt*10 + ks)*64 + ln)*8 + jj;
        Bhi[fo] = (__bf16)0.f;
        Blo[fo] = (__bf16)0.f;
    }
    for (int nh = t; nh < 3968; nh += 256)
        cpart += linb[nh & 63] * colo[nh];
    __syncthreads();
    redbuf[t] = cpart;
    __syncthreads();
    for (int sft = 128; sft > 0; sft >>= 1) {
        if (t < sft) redbuf[t] += redbuf[t + sft];
        __syncthreads();
    }
    if (t == 0) constv[o] = redbuf[0] + fc1b[o];
}

// --------------- K3: MFMA GEMM, A-frags formed in-register from X
// 512 blocks x 256 thr (4 waves); wave = 16 rows x 64 cols, K=320 (zero-pad).
__device__ __forceinline__ void loadA(const float* __restrict__ xrow, int q,
                                      int ks, bf16x8& ah, bf16x8& al)
{
    float v[8];
    if (ks < 9 || q < 2) {          // compile-time for ks<9 after unroll
        float2 a = *reinterpret_cast<const float2*>(xrow + ks*32);
        float2 b = *reinterpret_cast<const float2*>(xrow + ks*32 + 2);
        float2 c = *reinterpret_cast<const float2*>(xrow + ks*32 + 4);
        float2 d = *reinterpret_cast<const float2*>(xrow + ks*32 + 6);
        v[0]=a.x; v[1]=a.y; v[2]=b.x; v[3]=b.y;
        v[4]=c.x; v[5]=c.y; v[6]=d.x; v[7]=d.y;
    } else if (q == 2) {            // k 304..309 valid, 310..311 zero
        float2 a = *reinterpret_cast<const float2*>(xrow + ks*32);
        float2 b = *reinterpret_cast<const float2*>(xrow + ks*32 + 2);
        float2 c = *reinterpret_cast<const float2*>(xrow + ks*32 + 4);
        v[0]=a.x; v[1]=a.y; v[2]=b.x; v[3]=b.y;
        v[4]=c.x; v[5]=c.y; v[6]=0.f; v[7]=0.f;
    } else {                        // q == 3: k 312..319 all zero-pad
#pragma unroll
        for (int j = 0; j < 8; ++j) v[j] = 0.f;
    }
#pragma unroll
    for (int j = 0; j < 8; ++j) {
        __bf16 h = (__bf16)v[j];
        ah[j] = h;
        al[j] = (__bf16)(v[j] - (float)h);
    }
}

__global__ __launch_bounds__(256) void k_gemm(
    const float* __restrict__ X,
    const bf16x8* __restrict__ Bhi, const bf16x8* __restrict__ Blo,
    const float* __restrict__ constv, const float* __restrict__ fc2W,
    const float* __restrict__ fc2b, float* __restrict__ out)
{
    const int t = threadIdx.x;
    const int lane = t & 63;
    const int waveId = blockIdx.x * 4 + (t >> 6);   // 0..2047, 16 rows each
    const int rl = lane & 15;
    const int q  = lane >> 4;
    const float* xrow = X + (size_t)(waveId*16 + rl)*310 + q*8;
    const bf16x8* pBh = Bhi + lane;
    const bf16x8* pBl = Blo + lane;

    f32x4 acc[4];
#pragma unroll
    for (int n = 0; n < 4; ++n) acc[n] = (f32x4){0.f,0.f,0.f,0.f};

    bf16x8 ah[2], al[2], bh[2][4], bl[2][4];
#define LOAD_B(B_, KS_) do {                                              \
        bh[B_][0] = pBh[(KS_)*64];        bh[B_][1] = pBh[(10+(KS_))*64]; \
        bh[B_][2] = pBh[(20+(KS_))*64];   bh[B_][3] = pBh[(30+(KS_))*64]; \
        bl[B_][0] = pBl[(KS_)*64];        bl[B_][1] = pBl[(10+(KS_))*64]; \
        bl[B_][2] = pBl[(20+(KS_))*64];   bl[B_][3] = pBl[(30+(KS_))*64]; \
    } while (0)

    loadA(xrow, q, 0, ah[0], al[0]);
    LOAD_B(0, 0);
#pragma unroll
    for (int ks = 0; ks < 10; ++ks) {
        const int cur = ks & 1, nxt = cur ^ 1;
        if (ks < 9) {
            loadA(xrow, q, ks + 1, ah[nxt], al[nxt]);
            LOAD_B(nxt, ks + 1);
        }
#pragma unroll
        for (int n = 0; n < 4; ++n) {
            acc[n] = __builtin_amdgcn_mfma_f32_16x16x32_bf16(ah[cur], bh[cur][n], acc[n], 0, 0, 0);
            acc[n] = __builtin_amdgcn_mfma_f32_16x16x32_bf16(ah[cur], bl[cur][n], acc[n], 0, 0, 0);
            acc[n] = __builtin_amdgcn_mfma_f32_16x16x32_bf16(al[cur], bh[cur][n], acc[n], 0, 0, 0);
        }
    }
#undef LOAD_B

    // epilogue: z = relu(acc + const[col]); out3 = z @ fc2 (reduce 16 col-lanes)
    float cst[4], f2r[4][3];
#pragma unroll
    for (int n = 0; n < 4; ++n) {
        int col = n*16 + rl;
        cst[n]    = constv[col];
        f2r[n][0] = fc2W[col*3 + 0];
        f2r[n][1] = fc2W[col*3 + 1];
        f2r[n][2] = fc2W[col*3 + 2];
    }
    float b0 = fc2b[0], b1 = fc2b[1], b2 = fc2b[2];
#pragma unroll
    for (int r = 0; r < 4; ++r) {
        float p0 = 0.f, p1 = 0.f, p2 = 0.f;
#pragma unroll
        for (int n = 0; n < 4; ++n) {
            float z = fmaxf(acc[n][r] + cst[n], 0.f);
            p0 += z * f2r[n][0];
            p1 += z * f2r[n][1];
            p2 += z * f2r[n][2];
        }
#pragma unroll
        for (int msk = 1; msk < 16; msk <<= 1) {
            p0 += __shfl_xor(p0, msk);
            p1 += __shfl_xor(p1, msk);
            p2 += __shfl_xor(p2, msk);
        }
        if (rl == 0) {
            int row = waveId*16 + q*4 + r;
            size_t rw = (size_t)row * 3;
            out[rw + 0] = p0 + b0;
            out[rw + 1] = p1 + b1;
            out[rw + 2] = p2 + b2;
        }
    }
}

extern "C" void kernel_launch(void* const* d_in, const int* in_sizes, int n_in,
                              void* d_out, int out_size, void* d_ws, size_t ws_size,
                              hipStream_t stream)
{
    const float* X     = (const float*)d_in[0];
    const float* edge  = (const float*)d_in[1];
    const float* gamma = (const float*)d_in[2];
    const float* beta  = (const float*)d_in[3];
    const float* linW  = (const float*)d_in[4];
    const float* linb  = (const float*)d_in[5];
    const float* fc1W  = (const float*)d_in[6];
    const float* fc1b  = (const float*)d_in[7];
    const float* fc2W  = (const float*)d_in[8];
    const float* fc2b  = (const float*)d_in[9];
    float* out = (float*)d_out;
    float* ws  = (float*)d_ws;

    float*  part   = ws;                    // 496*10
    float*  S2g    = ws + 4960;             // 62*64
    float*  constv = ws + 8928;             // 64
    __bf16* Bhi    = (__bf16*)(ws + 8992);  // 2560 frags x 16B
    __bf16* Blo    = (__bf16*)(ws + 19232);

    hipLaunchKernelGGL(k_stats, dim3(497), dim3(256), 0, stream, X, edge, part, S2g);
    hipLaunchKernelGGL(k_setup, dim3(64),  dim3(256), 0, stream,
                       part, S2g, gamma, beta, linW, linb, fc1W, fc1b, Bhi, Blo, constv);
    hipLaunchKernelGGL(k_gemm,  dim3(512), dim3(256), 0, stream,
                       X, (const bf16x8*)Bhi, (const bf16x8*)Blo,
                       constv, fc2W, fc2b, out);
}

// Round 6
// 127.775 us; speedup vs baseline: 1.3152x; 1.0111x over previous
//
#include <hip/hip_runtime.h>
#include <math.h>

// DGCNN forward, algebraically collapsed:
//   out = relu(X_flat @ Meff + const) @ fc2_W + fc2_b
// Meff (310x64) folds BN-scale, S^2, lin_W, fc1_W; const folds shifts/biases.
// GEMM on MFMA via split-bf16: x=hi+lo, M=hi+lo, acc = hi*hi + hi*lo + lo*hi.
//
// Pipeline (3 kernels):
//   k_stats : X -> BN stat partials (blocks 0..495); block 496 builds S^2
//   k_setup : stats -> scale/shift; T; B-fragments (bf16 hi/lo) + const
//   k_gemm  : ALL X loads hoisted up front (40 float2 in flight per lane,
//             full MLP), B-frags prefetched 2-ahead on a pure-B vmcnt chain,
//             16x16x32 bf16 MFMA, K=320, fused relu+fc2 epilogue
//
// ws layout (floats):
//   [0,4960)        BN stat partials (496 x 10)
//   [4960,8928)     S2 (62x64, pitch 64)
//   [8928,8992)     const (64)
//   [8992,19232)    Bhi frags (4nt x 10ks x 64lane x 16B)
//   [19232,29472)   Blo frags

typedef __attribute__((ext_vector_type(8))) __bf16 bf16x8;
typedef __attribute__((ext_vector_type(4))) float f32x4;

#define BN_COUNT 2031616.0f   // B*N = 32768*62

// --------------------- K1: BN stat partials; block 496 builds S^2
__global__ __launch_bounds__(256) void k_stats(const float* __restrict__ X,
                                               const float* __restrict__ edge,
                                               float* __restrict__ part,
                                               float* __restrict__ S2g)
{
    __shared__ __align__(16) float lds[4160];
    const int t = threadIdx.x;
    if (blockIdx.x < 496) {
        int tid = blockIdx.x * 256 + t;
        const float4* Xv = reinterpret_cast<const float4*>(X) + (size_t)tid * 20;
        float s[5] = {0.f,0.f,0.f,0.f,0.f};
        float q[5] = {0.f,0.f,0.f,0.f,0.f};
#pragma unroll
        for (int v = 0; v < 20; ++v) {
            float4 x = Xv[v];
            s[(4*v+0)%5] += x.x; q[(4*v+0)%5] += x.x*x.x;
            s[(4*v+1)%5] += x.y; q[(4*v+1)%5] += x.y*x.y;
            s[(4*v+2)%5] += x.z; q[(4*v+2)%5] += x.z*x.z;
            s[(4*v+3)%5] += x.w; q[(4*v+3)%5] += x.w*x.w;
        }
#pragma unroll
        for (int k = 0; k < 5; ++k)
#pragma unroll
            for (int m = 32; m >= 1; m >>= 1) {
                s[k] += __shfl_xor(s[k], m);
                q[k] += __shfl_xor(q[k], m);
            }
        int lane = t & 63, w = t >> 6;
        if (lane == 0) {
#pragma unroll
            for (int k = 0; k < 5; ++k) { lds[w*10+k] = s[k]; lds[w*10+5+k] = q[k]; }
        }
        __syncthreads();
        if (t < 10)
            part[blockIdx.x*10 + t] = lds[t] + lds[10+t] + lds[20+t] + lds[30+t];
    } else {
        // build S (62x62, pitch 64, zero-padded) then S2 = S@S
        float* Sm  = lds;          // 62*64
        float* dv  = lds + 3968;   // 64
        float* dis = lds + 4032;   // 64
        for (int e = t; e < 3968; e += 256) {
            int i = e >> 6, j = e & 63;
            float v = 0.f;
            if (j < 62) {
                int idx = (i >= j) ? (i*(i+1)/2 + j) : (j*(j+1)/2 + i);
                v = fmaxf(edge[idx], 0.f);
            }
            Sm[e] = v;
        }
        __syncthreads();
        if (t < 62) {
            float s = 0.f;
            for (int j = 0; j < 64; ++j) s += Sm[t*64 + j];
            dv[t] = 1.0f / sqrtf(s + 1e-10f);
        }
        __syncthreads();
        for (int e = t; e < 3968; e += 256) {
            int i = e >> 6, j = e & 63;
            if (j < 62) Sm[e] *= dv[i] * dv[j];
        }
        __syncthreads();
        if (t < 62) {
            float dg = 1.0f;
            for (int j = 0; j < 64; ++j) dg += fabsf(Sm[t*64 + j]);
            dis[t] = 1.0f / sqrtf(dg);
        }
        __syncthreads();
        for (int e = t; e < 3968; e += 256) {
            int i = e >> 6, j = e & 63;
            if (j < 62) {
                float v = Sm[e] + ((i == j) ? 1.0f : 0.0f);
                Sm[e] = dis[i] * v * dis[j];
            }
        }
        __syncthreads();
        for (int g = t; g < 992; g += 256) {
            int i = g >> 4, j0 = (g & 15) << 2;
            float4 acc = {0.f, 0.f, 0.f, 0.f};
            for (int k = 0; k < 62; ++k) {
                float s = Sm[i*64 + k];
                float4 b = *reinterpret_cast<const float4*>(&Sm[k*64 + j0]);
                acc.x += s*b.x; acc.y += s*b.y; acc.z += s*b.z; acc.w += s*b.w;
            }
            *reinterpret_cast<float4*>(&S2g[i*64 + j0]) = acc;
        }
    }
}

// ------------------- K2: build B fragments (bf16 hi/lo) + const; 64 blocks
__global__ __launch_bounds__(256) void k_setup(
    const float* __restrict__ part, const float* __restrict__ S2g,
    const float* __restrict__ gamma, const float* __restrict__ beta,
    const float* __restrict__ linW, const float* __restrict__ linb,
    const float* __restrict__ fc1W, const float* __restrict__ fc1b,
    __bf16* __restrict__ Bhi, __bf16* __restrict__ Blo,
    float* __restrict__ constv)
{
    const int o = blockIdx.x;
    const int t = threadIdx.x;
    __shared__ float S2m[3968];
    __shared__ float colo[3968];
    __shared__ float Tm[310];
    __shared__ float lw[320];
    __shared__ float scale[5], shift[5];
    __shared__ float redbuf[256];

    {   // BN stats reduce over 496 partials
        float st[10];
#pragma unroll
        for (int k = 0; k < 10; ++k) st[k] = 0.f;
        for (int b = t; b < 496; b += 256)
#pragma unroll
            for (int k = 0; k < 10; ++k) st[k] += part[b*10 + k];
#pragma unroll
        for (int k = 0; k < 10; ++k)
#pragma unroll
            for (int m = 32; m >= 1; m >>= 1) st[k] += __shfl_xor(st[k], m);
        int lane = t & 63, w = t >> 6;
        if (lane == 0)
            for (int k = 0; k < 10; ++k) redbuf[w*10 + k] = st[k];
    }
    for (int i = t; i < 3968; i += 256) {
        S2m[i]  = S2g[i];
        colo[i] = fc1W[(size_t)i*64 + o];
    }
    for (int i = t; i < 320; i += 256) lw[i] = linW[i];
    __syncthreads();

    if (t < 10)
        redbuf[64 + t] = redbuf[t] + redbuf[10+t] + redbuf[20+t] + redbuf[30+t];
    __syncthreads();
    if (t < 5) {
        float mean = redbuf[64 + t] * (1.0f / BN_COUNT);
        float var  = redbuf[69 + t] * (1.0f / BN_COUNT) - mean*mean;
        float inv  = 1.0f / sqrtf(var + 1e-5f);
        scale[t] = gamma[t] * inv;
        shift[t] = beta[t] - mean * gamma[t] * inv;
    }
    // T[n,f] = sum_h lin_W[f,h] * fc1W[n*64+h, o]
    for (int p = t; p < 310; p += 256) {
        int n = p / 5, f = p - n*5;
        float sum = 0.f;
        for (int h = 0; h < 64; ++h) sum += lw[f*64 + h] * colo[n*64 + h];
        Tm[p] = sum;
    }
    __syncthreads();
    // Meff[p] = scale[f] * sum_n S2[n,nd] T[n,f]  (p = nd*5+f = k index)
    // written directly as bf16 hi/lo B-fragments
    const int nt = o >> 4;
    const int cl = o & 15;
    float cpart = 0.f;
    for (int p = t; p < 310; p += 256) {
        int nd = p / 5, f = p - nd*5;
        float m = 0.f;
        for (int n = 0; n < 62; ++n) m += S2m[n*64 + nd] * Tm[n*5 + f];
        float val = scale[f] * m;
        cpart += shift[f] * m;
        int ks = p >> 5, qq = (p >> 3) & 3, jj = p & 7;
        int ln = (qq << 4) | cl;
        size_t fo = ((size_t)(nt*10 + ks)*64 + ln)*8 + jj;
        __bf16 h = (__bf16)val;
        Bhi[fo] = h;
        Blo[fo] = (__bf16)(val - (float)h);
    }
    if (t < 10) {                       // zero-pad k = 310..319
        int p = 310 + t;
        int ks = p >> 5, qq = (p >> 3) & 3, jj = p & 7;
        int ln = (qq << 4) | cl;
        size_t fo = ((size_t)(nt*10 + ks)*64 + ln)*8 + jj;
        Bhi[fo] = (__bf16)0.f;
        Blo[fo] = (__bf16)0.f;
    }
    for (int nh = t; nh < 3968; nh += 256)
        cpart += linb[nh & 63] * colo[nh];
    __syncthreads();
    redbuf[t] = cpart;
    __syncthreads();
    for (int sft = 128; sft > 0; sft >>= 1) {
        if (t < sft) redbuf[t] += redbuf[t + sft];
        __syncthreads();
    }
    if (t == 0) constv[o] = redbuf[0] + fc1b[o];
}

// --------------- K3: MFMA GEMM, all X loads hoisted (full MLP)
// 512 blocks x 256 thr (4 waves); wave = 16 rows x 64 cols, K=320 (zero-pad).
__device__ __forceinline__ void cvt8(const float2* __restrict__ v,
                                     bf16x8& ah, bf16x8& al)
{
#pragma unroll
    for (int j = 0; j < 4; ++j) {
        __bf16 h0 = (__bf16)v[j].x;
        __bf16 h1 = (__bf16)v[j].y;
        ah[2*j]   = h0; al[2*j]   = (__bf16)(v[j].x - (float)h0);
        ah[2*j+1] = h1; al[2*j+1] = (__bf16)(v[j].y - (float)h1);
    }
}

__global__ __launch_bounds__(256) void k_gemm(
    const float* __restrict__ X,
    const bf16x8* __restrict__ Bhi, const bf16x8* __restrict__ Blo,
    const float* __restrict__ constv, const float* __restrict__ fc2W,
    const float* __restrict__ fc2b, float* __restrict__ out)
{
    const int t = threadIdx.x;
    const int lane = t & 63;
    const int waveId = blockIdx.x * 4 + (t >> 6);   // 0..2047, 16 rows each
    const int rl = lane & 15;
    const int q  = lane >> 4;
    const float* xrow = X + (size_t)(waveId*16 + rl)*310 + q*8;
    const bf16x8* pBh = Bhi + lane;
    const bf16x8* pBl = Blo + lane;

    bf16x8 bh[2][4], bl[2][4];
#define LOAD_B(B_, KS_) do {                                              \
        bh[B_][0] = pBh[(KS_)*64];        bh[B_][1] = pBh[(10+(KS_))*64]; \
        bh[B_][2] = pBh[(20+(KS_))*64];   bh[B_][3] = pBh[(30+(KS_))*64]; \
        bl[B_][0] = pBl[(KS_)*64];        bl[B_][1] = pBl[(10+(KS_))*64]; \
        bl[B_][2] = pBl[(20+(KS_))*64];   bl[B_][3] = pBl[(30+(KS_))*64]; \
    } while (0)

    // Issue B(0), B(1) FIRST (oldest on the vmcnt chain), then ALL X loads.
    LOAD_B(0, 0);
    LOAD_B(1, 1);

    float2 xv[40];                       // fully static indexing (no scratch)
#pragma unroll
    for (int ks = 0; ks < 10; ++ks) {
        if (ks < 9) {
#pragma unroll
            for (int j = 0; j < 4; ++j)
                xv[ks*4+j] = *reinterpret_cast<const float2*>(xrow + ks*32 + 2*j);
        }
    }
    // tail ks=9: k = q*8 + 288 + 2j; valid only below 310
    if (q < 2) {
#pragma unroll
        for (int j = 0; j < 4; ++j)
            xv[36+j] = *reinterpret_cast<const float2*>(xrow + 288 + 2*j);
    } else if (q == 2) {
#pragma unroll
        for (int j = 0; j < 3; ++j)
            xv[36+j] = *reinterpret_cast<const float2*>(xrow + 288 + 2*j);
        xv[39] = (float2){0.f, 0.f};
    } else {
#pragma unroll
        for (int j = 0; j < 4; ++j) xv[36+j] = (float2){0.f, 0.f};
    }

    f32x4 acc[4];
#pragma unroll
    for (int n = 0; n < 4; ++n) acc[n] = (f32x4){0.f,0.f,0.f,0.f};

#pragma unroll
    for (int ks = 0; ks < 10; ++ks) {
        bf16x8 ah, al;
        cvt8(&xv[ks*4], ah, al);
        const int cur = ks & 1;          // compile-time after full unroll
#pragma unroll
        for (int n = 0; n < 4; ++n) {
            acc[n] = __builtin_amdgcn_mfma_f32_16x16x32_bf16(ah, bh[cur][n], acc[n], 0, 0, 0);
            acc[n] = __builtin_amdgcn_mfma_f32_16x16x32_bf16(ah, bl[cur][n], acc[n], 0, 0, 0);
            acc[n] = __builtin_amdgcn_mfma_f32_16x16x32_bf16(al, bh[cur][n], acc[n], 0, 0, 0);
        }
        if (ks < 8) LOAD_B(cur, ks + 2); // refill slot for iteration ks+2
    }
#undef LOAD_B

    // epilogue: z = relu(acc + const[col]); out3 = z @ fc2 (reduce 16 col-lanes)
    float cst[4], f2r[4][3];
#pragma unroll
    for (int n = 0; n < 4; ++n) {
        int col = n*16 + rl;
        cst[n]    = constv[col];
        f2r[n][0] = fc2W[col*3 + 0];
        f2r[n][1] = fc2W[col*3 + 1];
        f2r[n][2] = fc2W[col*3 + 2];
    }
    float b0 = fc2b[0], b1 = fc2b[1], b2 = fc2b[2];
#pragma unroll
    for (int r = 0; r < 4; ++r) {
        float p0 = 0.f, p1 = 0.f, p2 = 0.f;
#pragma unroll
        for (int n = 0; n < 4; ++n) {
            float z = fmaxf(acc[n][r] + cst[n], 0.f);
            p0 += z * f2r[n][0];
            p1 += z * f2r[n][1];
            p2 += z * f2r[n][2];
        }
#pragma unroll
        for (int msk = 1; msk < 16; msk <<= 1) {
            p0 += __shfl_xor(p0, msk);
            p1 += __shfl_xor(p1, msk);
            p2 += __shfl_xor(p2, msk);
        }
        if (rl == 0) {
            int row = waveId*16 + q*4 + r;
            size_t rw = (size_t)row * 3;
            out[rw + 0] = p0 + b0;
            out[rw + 1] = p1 + b1;
            out[rw + 2] = p2 + b2;
        }
    }
}

extern "C" void kernel_launch(void* const* d_in, const int* in_sizes, int n_in,
                              void* d_out, int out_size, void* d_ws, size_t ws_size,
                              hipStream_t stream)
{
    const float* X     = (const float*)d_in[0];
    const float* edge  = (const float*)d_in[1];
    const float* gamma = (const float*)d_in[2];
    const float* beta  = (const float*)d_in[3];
    const float* linW  = (const float*)d_in[4];
    const float* linb  = (const float*)d_in[5];
    const float* fc1W  = (const float*)d_in[6];
    const float* fc1b  = (const float*)d_in[7];
    const float* fc2W  = (const float*)d_in[8];
    const float* fc2b  = (const float*)d_in[9];
    float* out = (float*)d_out;
    float* ws  = (float*)d_ws;

    float*  part   = ws;                    // 496*10
    float*  S2g    = ws + 4960;             // 62*64
    float*  constv = ws + 8928;             // 64
    __bf16* Bhi    = (__bf16*)(ws + 8992);  // 2560 frags x 16B
    __bf16* Blo    = (__bf16*)(ws + 19232);

    hipLaunchKernelGGL(k_stats, dim3(497), dim3(256), 0, stream, X, edge, part, S2g);
    hipLaunchKernelGGL(k_setup, dim3(64),  dim3(256), 0, stream,
                       part, S2g, gamma, beta, linW, linb, fc1W, fc1b, Bhi, Blo, constv);
    hipLaunchKernelGGL(k_gemm,  dim3(512), dim3(256), 0, stream,
                       X, (const bf16x8*)Bhi, (const bf16x8*)Blo,
                       constv, fc2W, fc2b, out);
}